// Round 7
// baseline (2034.934 us; speedup 1.0000x reference)
//
#include <hip/hip_runtime.h>
#include <cstdint>

#define SLEN 1024
#define BATCH 64
#define EDIM 256
#define HDIM 128   // hidden per direction
#define GDIM 512   // 4*HDIM
#define NTAG 4

typedef float f2 __attribute__((ext_vector_type(2)));

// ---------------------------------------------------------------------------
// ws layout (floats), chunked to fit ws_size:
//   Z  : [L][B][1024]  gate-preactivation chunk (cols 0..511 fwd, 512..1023 rev)
//   H  : [S][B][256]   (cols 0..127 fwd h, 128..255 rev h)      16777216
//   F  : [S][B][4]     emissions                                   262144
//   ST : [2][B][256]   LSTM carry (h | c) per (dir,b)               32768
// ---------------------------------------------------------------------------

__device__ __forceinline__ float sigm_f(float x) {
    return 1.0f / (1.0f + __expf(-x));
}
__device__ __forceinline__ float tanh_f(float x) {
    return 1.0f - 2.0f / (1.0f + __expf(2.0f * x));
}

template <int CTRL>
__device__ __forceinline__ float quad_perm(float x) {
    return __int_as_float(
        __builtin_amdgcn_mov_dpp(__float_as_int(x), CTRL, 0xF, 0xF, true));
}
#define QP_XOR1  0xB1    // quad_perm [1,0,3,2]
#define QP_XOR2  0x4E    // quad_perm [2,3,0,1]
#define QP_HMIRR 0x141   // row_half_mirror (reverse within 8 lanes)

// ---------------------------------------------------------------------------
// Kernel 1: fused embedding-gather + input-projection GEMM for one S-chunk.
// 128x128 tile, kc=64, 256 threads, 8x8 micro, pk-fma via f2.
// ---------------------------------------------------------------------------
__global__ __launch_bounds__(256) void gemm_zin(
    const int* __restrict__ sent, const float* __restrict__ embed,
    const float* __restrict__ w_ih_f, const float* __restrict__ w_ih_r,
    const float* __restrict__ b_ih_f, const float* __restrict__ b_hh_f,
    const float* __restrict__ b_ih_r, const float* __restrict__ b_hh_r,
    float* __restrict__ Z, int base_f, int base_r)
{
    __shared__ __align__(16) float As[64 * 128];
    __shared__ __align__(16) float Bs[64 * 128];

    const int t   = threadIdx.x;
    const int mt  = blockIdx.x;
    const int nt  = blockIdx.y;
    const int dir = nt >> 2;
    const float* W  = dir ? w_ih_r : w_ih_f;
    const float* bi = dir ? b_ih_r : b_ih_f;
    const float* bh = dir ? b_hh_r : b_hh_f;
    const int ncol = (nt & 3) * 128;
    const int r0   = mt * 128;

    const int srow = t >> 1;
    const int half = t & 1;
    const int r_loc = r0 + srow;
    const int s_loc = r_loc >> 6;
    const int b_    = r_loc & 63;
    const int s_glob = (dir ? base_r : base_f) + s_loc;
    const int tok = sent[b_ * SLEN + s_glob];
    const float* arow = embed + (size_t)tok * EDIM + half * 32;
    const float* brow = W + (size_t)(ncol + srow) * EDIM + half * 32;

    const int tx = t & 15, ty = t >> 4;

    f2 acc[8][4];
    #pragma unroll
    for (int i = 0; i < 8; ++i)
        #pragma unroll
        for (int jj = 0; jj < 4; ++jj) { acc[i][jj] = (f2)(0.0f); }

    for (int kt = 0; kt < 4; ++kt) {
        const int k0 = kt * 64;
        __syncthreads();
        #pragma unroll
        for (int i = 0; i < 8; ++i) {
            float4 v = *(const float4*)(arow + k0 + i * 4);
            int kk = half * 32 + i * 4;
            As[(kk + 0) * 128 + srow] = v.x;
            As[(kk + 1) * 128 + srow] = v.y;
            As[(kk + 2) * 128 + srow] = v.z;
            As[(kk + 3) * 128 + srow] = v.w;
        }
        #pragma unroll
        for (int i = 0; i < 8; ++i) {
            float4 v = *(const float4*)(brow + k0 + i * 4);
            int kk = half * 32 + i * 4;
            Bs[(kk + 0) * 128 + srow] = v.x;
            Bs[(kk + 1) * 128 + srow] = v.y;
            Bs[(kk + 2) * 128 + srow] = v.z;
            Bs[(kk + 3) * 128 + srow] = v.w;
        }
        __syncthreads();

        #pragma unroll 8
        for (int k = 0; k < 64; ++k) {
            const float4 a0 = *(const float4*)&As[k * 128 + ty * 8];
            const float4 a1 = *(const float4*)&As[k * 128 + ty * 8 + 4];
            const float4 bq0 = *(const float4*)&Bs[k * 128 + tx * 8];
            const float4 bq1 = *(const float4*)&Bs[k * 128 + tx * 8 + 4];
            float av[8] = {a0.x, a0.y, a0.z, a0.w, a1.x, a1.y, a1.z, a1.w};
            f2 bv[4];
            bv[0].x = bq0.x; bv[0].y = bq0.y;
            bv[1].x = bq0.z; bv[1].y = bq0.w;
            bv[2].x = bq1.x; bv[2].y = bq1.y;
            bv[3].x = bq1.z; bv[3].y = bq1.w;
            #pragma unroll
            for (int i = 0; i < 8; ++i) {
                f2 as; as.x = av[i]; as.y = av[i];
                #pragma unroll
                for (int jj = 0; jj < 4; ++jj) {
                    acc[i][jj] += as * bv[jj];   // v_pk_fma_f32
                }
            }
        }
    }

    float bias[8];
    #pragma unroll
    for (int jj = 0; jj < 8; ++jj)
        bias[jj] = bi[ncol + tx * 8 + jj] + bh[ncol + tx * 8 + jj];

    #pragma unroll
    for (int i = 0; i < 8; ++i) {
        int rr = r0 + ty * 8 + i;
        float* zp = Z + (size_t)rr * 1024 + dir * 512 + ncol + tx * 8;
        float4 o0, o1;
        o0.x = acc[i][0].x + bias[0]; o0.y = acc[i][0].y + bias[1];
        o0.z = acc[i][1].x + bias[2]; o0.w = acc[i][1].y + bias[3];
        o1.x = acc[i][2].x + bias[4]; o1.y = acc[i][2].y + bias[5];
        o1.z = acc[i][3].x + bias[6]; o1.w = acc[i][3].y + bias[7];
        *(float4*)zp       = o0;
        *(float4*)(zp + 4) = o1;
    }
}

// ---------------------------------------------------------------------------
// Kernel 2 (v4): LSTM recurrence, W truly VGPR-resident.
// 128 blocks (batch x dir), 512 threads (8 waves).
// Octet o=q>>3 owns units uA=o, uB=o+64; lane r=q&7 owns k in [16r,16r+16).
// Per lane: 8 dots x 16k = 128 W floats (64 f2) in VGPRs.
// Reduce: all-DPP 8-lane butterfly (xor1, xor2, half-mirror) -> every lane
// holds all 8 full preactivations; gates replicated. Z: ONE dword load per
// wave per step (lane r owns dot d=r), injected predicated pre-butterfly.
// h ping-pong in LDS, 20-float-strided chunks (8 distinct b128 addrs ->
// 8 distinct bank groups, conflict-free). 1 barrier/step.
// ---------------------------------------------------------------------------
__global__ __launch_bounds__(512, 2) void lstm_rec(
    const float* __restrict__ Z, const float* __restrict__ w_hh_f,
    const float* __restrict__ w_hh_r, float* __restrict__ H,
    float* __restrict__ ST, int base_f, int base_r, int L, int first)
{
    const int bid = blockIdx.x;
    const int b   = bid & 63;
    const int dir = bid >> 6;
    const int q   = threadIdx.x;
    const int r   = q & 7;    // k-slice lane
    const int o   = q >> 3;   // octet id = unit uA
    const int uA  = o;
    const int uB  = o + 64;

    const float* Whh = dir ? w_hh_r : w_hh_f;

    // register-resident weights: dot d=(u2*4+g), k in [16r,16r+16): 8 f2 each
    f2 w[8][8];
    #pragma unroll
    for (int u2 = 0; u2 < 2; ++u2) {
        const int u = u2 ? uB : uA;
        #pragma unroll
        for (int g = 0; g < 4; ++g) {
            const float4* src =
                (const float4*)(Whh + ((size_t)(g * 128 + u) * 128 + r * 16));
            #pragma unroll
            for (int i = 0; i < 4; ++i) {
                float4 v = src[i];
                w[u2 * 4 + g][2 * i].x     = v.x; w[u2 * 4 + g][2 * i].y     = v.y;
                w[u2 * 4 + g][2 * i + 1].x = v.z; w[u2 * 4 + g][2 * i + 1].y = v.w;
            }
        }
    }

    // h ping-pong: h[k] at chunk (k>>4)*20 + (k&15); chunk stride 20 floats
    // -> 8 distinct b128 addresses per read inst land in 8 bank groups.
    __shared__ __align__(16) float sh_h[2][160];

    float* stp = ST + (size_t)(dir * 64 + b) * 256;
    if (q < 128)
        sh_h[0][(q >> 4) * 20 + (q & 15)] = first ? 0.0f : stp[q];
    float cA = first ? 0.0f : stp[128 + uA];
    float cB = first ? 0.0f : stp[128 + uB];

    // per-lane Z element: dot d=r -> u2=r>>2, g=r&3
    const float* Zbase = Z + (size_t)b * 1024 + dir * 512
                       + (r & 3) * 128 + o + ((r >> 2) << 6);
    float zcur[4], znxt[4];
    #pragma unroll
    for (int dt = 0; dt < 4; ++dt) {
        const int s_loc = dir ? (L - 1 - dt) : dt;
        zcur[dt] = Zbase[(size_t)s_loc * 65536];
    }
    __syncthreads();

    float hAo[4], hBo[4];

    for (int t0 = 0; t0 < L; t0 += 4) {
        const bool more = (t0 + 4 < L);
        if (more) {
            #pragma unroll
            for (int dt = 0; dt < 4; ++dt) {
                const int tt = t0 + 4 + dt;
                const int s_loc = dir ? (L - 1 - tt) : tt;
                znxt[dt] = Zbase[(size_t)s_loc * 65536];
            }
        }

        #pragma unroll
        for (int dt = 0; dt < 4; ++dt) {
            const int t = t0 + dt;
            // read this lane's 16-float h slice (4 conflict-free b128)
            const float4* hp = (const float4*)(&sh_h[t & 1][0] + r * 20);
            f2 hv[8];
            #pragma unroll
            for (int i = 0; i < 4; ++i) {
                float4 v = hp[i];
                hv[2 * i].x     = v.x; hv[2 * i].y     = v.y;
                hv[2 * i + 1].x = v.z; hv[2 * i + 1].y = v.w;
            }
            // 8 partial dots over 16 k, z injected in owning lane
            float zd[8];
            #pragma unroll
            for (int d = 0; d < 8; ++d) {
                f2 a = (f2)(0.0f);
                #pragma unroll
                for (int i = 0; i < 8; ++i)
                    a += w[d][i] * hv[i];        // v_pk_fma_f32
                float v = a.x + a.y;
                v += (d == r) ? zcur[dt] : 0.0f;
                zd[d] = v;
            }
            // 8-lane all-DPP butterfly: all lanes get all 8 full sums
            #pragma unroll
            for (int d = 0; d < 8; ++d) {
                float v = zd[d];
                v += quad_perm<QP_XOR1>(v);
                v += quad_perm<QP_XOR2>(v);
                v += quad_perm<QP_HMIRR>(v);
                zd[d] = v;
            }
            // gates (replicated across octet)
            float iA = sigm_f(zd[0]), fA = sigm_f(zd[1]);
            float gA = tanh_f(zd[2]), oA = sigm_f(zd[3]);
            cA = fA * cA + iA * gA;
            float hA = oA * tanh_f(cA);
            float iB = sigm_f(zd[4]), fB = sigm_f(zd[5]);
            float gB = tanh_f(zd[6]), oB = sigm_f(zd[7]);
            cB = fB * cB + iB * gB;
            float hB = oB * tanh_f(cB);
            hAo[dt] = hA; hBo[dt] = hB;

            float* hn = &sh_h[(t + 1) & 1][0];
            if (r == 0) hn[(uA >> 4) * 20 + (uA & 15)] = hA;
            if (r == 1) hn[(uB >> 4) * 20 + (uB & 15)] = hB;
            __syncthreads();
        }

        // buffered H stores (drain amortized over 4 steps)
        #pragma unroll
        for (int dt = 0; dt < 4; ++dt) {
            const int t = t0 + dt;
            const int s_glob = dir ? (base_r + (L - 1 - t)) : (base_f + t);
            float* hg = H + ((size_t)s_glob * 64 + b) * 256 + dir * 128;
            if (r == 0) hg[uA] = hAo[dt];
            if (r == 1) hg[uB] = hBo[dt];
        }
        if (more) {
            #pragma unroll
            for (int dt = 0; dt < 4; ++dt) zcur[dt] = znxt[dt];
        }
    }

    if (r == 0) { stp[uA] = hAo[3]; stp[128 + uA] = cA; }
    if (r == 1) { stp[uB] = hBo[3]; stp[128 + uB] = cB; }
}

// ---------------------------------------------------------------------------
// Kernel 3: emissions  F[r][t] = H[r] . w_out[t] + b_out[t]
// ---------------------------------------------------------------------------
__global__ __launch_bounds__(256) void emissions_k(
    const float* __restrict__ H, const float* __restrict__ w_out,
    const float* __restrict__ b_out, float* __restrict__ F)
{
    const int gid = blockIdx.x * 256 + threadIdx.x;
    const int r   = gid >> 2;
    const int tg  = gid & 3;
    const float4* h4 = (const float4*)(H + (size_t)r * 256);
    const float4* w4 = (const float4*)(w_out + (size_t)tg * 256);
    float a0 = 0.f, a1 = 0.f, a2 = 0.f, a3 = 0.f;
    #pragma unroll 8
    for (int k = 0; k < 64; ++k) {
        float4 h = h4[k], w = w4[k];
        a0 = fmaf(h.x, w.x, a0); a1 = fmaf(h.y, w.y, a1);
        a2 = fmaf(h.z, w.z, a2); a3 = fmaf(h.w, w.w, a3);
    }
    F[gid] = ((a0 + a1) + (a2 + a3)) + b_out[tg];
}

// ---------------------------------------------------------------------------
// Kernel 4: Viterbi. One block (1 wave) per batch.
// ---------------------------------------------------------------------------
__device__ __forceinline__ unsigned compose_map(unsigned a, unsigned b) {
    unsigned r = 0;
    #pragma unroll
    for (int jj = 0; jj < 4; ++jj) {
        unsigned bj = (b >> (jj * 8)) & 3u;
        unsigned aj = (a >> (bj * 8)) & 3u;
        r |= aj << (jj * 8);
    }
    return r;
}

__global__ __launch_bounds__(64) void viterbi_k(
    const float* __restrict__ F, const float* __restrict__ start_t,
    const float* __restrict__ end_t, const float* __restrict__ trans,
    int* __restrict__ out)
{
    const int b    = blockIdx.x;
    const int lane = threadIdx.x;
    __shared__ __align__(16) float sfeat[SLEN][NTAG];
    __shared__ unsigned sbp[SLEN];

    #pragma unroll
    for (int i = 0; i < 16; ++i) {
        int s = i * 64 + lane;
        ((float4*)sfeat)[s] = *(const float4*)(F + ((size_t)s * BATCH + b) * NTAG);
    }
    __syncthreads();

    const int cur = lane & 3;
    float tr0 = trans[0 * 4 + cur], tr1 = trans[1 * 4 + cur];
    float tr2 = trans[2 * 4 + cur], tr3 = trans[3 * 4 + cur];
    float sc = start_t[cur] + sfeat[0][cur];

    for (int s = 1; s < SLEN; ++s) {
        float ft = sfeat[s][cur];
        float s0 = __shfl(sc, 0), s1 = __shfl(sc, 1);
        float s2 = __shfl(sc, 2), s3 = __shfl(sc, 3);
        float c0 = s0 + tr0, c1 = s1 + tr1, c2 = s2 + tr2, c3 = s3 + tr3;
        float best = c0; int arg = 0;
        if (c1 > best) { best = c1; arg = 1; }
        if (c2 > best) { best = c2; arg = 2; }
        if (c3 > best) { best = c3; arg = 3; }
        sc = best + ft;
        unsigned bp = (unsigned)arg;
        unsigned b0 = __shfl(bp, 0), b1 = __shfl(bp, 1);
        unsigned b2 = __shfl(bp, 2), b3 = __shfl(bp, 3);
        if (lane == 0) sbp[s] = b0 | (b1 << 8) | (b2 << 16) | (b3 << 24);
    }
    sc += end_t[cur];
    float f0 = __shfl(sc, 0), f1 = __shfl(sc, 1);
    float f2v = __shfl(sc, 2), f3 = __shfl(sc, 3);
    int last = 0; float bb = f0;
    if (f1 > bb)  { bb = f1;  last = 1; }
    if (f2v > bb) { bb = f2v; last = 2; }
    if (f3 > bb)  { bb = f3;  last = 3; }
    __syncthreads();

    unsigned m[16];
    #pragma unroll
    for (int k = 0; k < 16; ++k) {
        int s = lane * 16 + k;
        m[k] = (s >= 1) ? sbp[s] : 0x03020100u;
    }
    unsigned G = m[15];
    #pragma unroll
    for (int k = 14; k >= 0; --k) G = compose_map(m[k], G);
    unsigned R = G;
    #pragma unroll
    for (int d = 1; d < 64; d <<= 1) {
        unsigned oo = __shfl_down(R, d);
        if (lane + d < 64) R = compose_map(R, oo);
    }
    unsigned P = __shfl_down(R, 1);
    if (lane == 63) P = 0x03020100u;

    int tcur = (int)((P >> (last * 8)) & 3u);
    int* ob = out + b * SLEN + lane * 16;
    ob[15] = tcur;
    #pragma unroll
    for (int k = 15; k >= 1; --k) {
        tcur = (int)((m[k] >> (tcur * 8)) & 3u);
        ob[k - 1] = tcur;
    }
}

// ---------------------------------------------------------------------------
extern "C" void kernel_launch(void* const* d_in, const int* in_sizes, int n_in,
                              void* d_out, int out_size, void* d_ws, size_t ws_size,
                              hipStream_t stream)
{
    const int*   sent    = (const int*)d_in[0];
    const float* embed   = (const float*)d_in[1];
    const float* w_ih_f  = (const float*)d_in[2];
    const float* w_hh_f  = (const float*)d_in[3];
    const float* b_ih_f  = (const float*)d_in[4];
    const float* b_hh_f  = (const float*)d_in[5];
    const float* w_ih_r  = (const float*)d_in[6];
    const float* w_hh_r  = (const float*)d_in[7];
    const float* b_ih_r  = (const float*)d_in[8];
    const float* b_hh_r  = (const float*)d_in[9];
    const float* w_out   = (const float*)d_in[10];
    const float* b_out   = (const float*)d_in[11];
    const float* start_t = (const float*)d_in[12];
    const float* end_t   = (const float*)d_in[13];
    const float* trans   = (const float*)d_in[14];
    int* out = (int*)d_out;

    const size_t H_FLOATS  = (size_t)SLEN * BATCH * 256;   // 16777216
    const size_t F_FLOATS  = (size_t)SLEN * BATCH * NTAG;  //   262144
    const size_t ST_FLOATS = (size_t)2 * BATCH * 256;      //    32768
    const size_t FIXED = H_FLOATS + F_FLOATS + ST_FLOATS;

    int L = SLEN;
    while (L > 32) {
        size_t need = ((size_t)L * BATCH * 1024 + FIXED) * sizeof(float);
        if (need <= ws_size) break;
        L >>= 1;
    }

    float* Z  = (float*)d_ws;
    float* H  = Z + (size_t)L * BATCH * 1024;
    float* F  = H + H_FLOATS;
    float* ST = F + F_FLOATS;

    const int nch = SLEN / L;
    for (int c = 0; c < nch; ++c) {
        const int base_f = c * L;
        const int base_r = SLEN - (c + 1) * L;
        gemm_zin<<<dim3(L / 2, 8), 256, 0, stream>>>(
            sent, embed, w_ih_f, w_ih_r, b_ih_f, b_hh_f, b_ih_r, b_hh_r,
            Z, base_f, base_r);
        lstm_rec<<<128, 512, 0, stream>>>(
            Z, w_hh_f, w_hh_r, H, ST, base_f, base_r, L, c == 0 ? 1 : 0);
    }
    emissions_k<<<1024, 256, 0, stream>>>(H, w_out, b_out, F);
    viterbi_k<<<64, 64, 0, stream>>>(F, start_t, end_t, trans, out);
}

// Round 8
// 1980.987 us; speedup vs baseline: 1.0272x; 1.0272x over previous
//
#include <hip/hip_runtime.h>
#include <cstdint>

#define SLEN 1024
#define BATCH 64
#define EDIM 256
#define HDIM 128   // hidden per direction
#define GDIM 512   // 4*HDIM
#define NTAG 4

typedef float f2 __attribute__((ext_vector_type(2)));

// ---------------------------------------------------------------------------
// ws layout (floats), chunked to fit ws_size:
//   Z  : [L][B][1024]  gate-preactivation chunk (cols 0..511 fwd, 512..1023 rev)
//   H  : [S][B][256]   (cols 0..127 fwd h, 128..255 rev h)      16777216
//   F  : [S][B][4]     emissions                                   262144
//   ST : [2][B][256]   LSTM carry (h | c) per (dir,b)               32768
// ---------------------------------------------------------------------------

__device__ __forceinline__ float sigm_f(float x) {
    return 1.0f / (1.0f + __expf(-x));
}
__device__ __forceinline__ float tanh_f(float x) {
    return 1.0f - 2.0f / (1.0f + __expf(2.0f * x));
}

template <int CTRL>
__device__ __forceinline__ float quad_perm(float x) {
    return __int_as_float(
        __builtin_amdgcn_mov_dpp(__float_as_int(x), CTRL, 0xF, 0xF, true));
}
#define QP_XOR1  0xB1    // quad_perm [1,0,3,2]
#define QP_XOR2  0x4E    // quad_perm [2,3,0,1]
#define QP_HMIRR 0x141   // row_half_mirror (reverse within 8 lanes)

// ---------------------------------------------------------------------------
// Kernel 1: fused embedding-gather + input-projection GEMM for one S-chunk.
// 128x128 tile, kc=64, 256 threads, 8x8 micro, pk-fma via f2.
// ---------------------------------------------------------------------------
__global__ __launch_bounds__(256) void gemm_zin(
    const int* __restrict__ sent, const float* __restrict__ embed,
    const float* __restrict__ w_ih_f, const float* __restrict__ w_ih_r,
    const float* __restrict__ b_ih_f, const float* __restrict__ b_hh_f,
    const float* __restrict__ b_ih_r, const float* __restrict__ b_hh_r,
    float* __restrict__ Z, int base_f, int base_r)
{
    __shared__ __align__(16) float As[64 * 128];
    __shared__ __align__(16) float Bs[64 * 128];

    const int t   = threadIdx.x;
    const int mt  = blockIdx.x;
    const int nt  = blockIdx.y;
    const int dir = nt >> 2;
    const float* W  = dir ? w_ih_r : w_ih_f;
    const float* bi = dir ? b_ih_r : b_ih_f;
    const float* bh = dir ? b_hh_r : b_hh_f;
    const int ncol = (nt & 3) * 128;
    const int r0   = mt * 128;

    const int srow = t >> 1;
    const int half = t & 1;
    const int r_loc = r0 + srow;
    const int s_loc = r_loc >> 6;
    const int b_    = r_loc & 63;
    const int s_glob = (dir ? base_r : base_f) + s_loc;
    const int tok = sent[b_ * SLEN + s_glob];
    const float* arow = embed + (size_t)tok * EDIM + half * 32;
    const float* brow = W + (size_t)(ncol + srow) * EDIM + half * 32;

    const int tx = t & 15, ty = t >> 4;

    f2 acc[8][4];
    #pragma unroll
    for (int i = 0; i < 8; ++i)
        #pragma unroll
        for (int jj = 0; jj < 4; ++jj) { acc[i][jj] = (f2)(0.0f); }

    for (int kt = 0; kt < 4; ++kt) {
        const int k0 = kt * 64;
        __syncthreads();
        #pragma unroll
        for (int i = 0; i < 8; ++i) {
            float4 v = *(const float4*)(arow + k0 + i * 4);
            int kk = half * 32 + i * 4;
            As[(kk + 0) * 128 + srow] = v.x;
            As[(kk + 1) * 128 + srow] = v.y;
            As[(kk + 2) * 128 + srow] = v.z;
            As[(kk + 3) * 128 + srow] = v.w;
        }
        #pragma unroll
        for (int i = 0; i < 8; ++i) {
            float4 v = *(const float4*)(brow + k0 + i * 4);
            int kk = half * 32 + i * 4;
            Bs[(kk + 0) * 128 + srow] = v.x;
            Bs[(kk + 1) * 128 + srow] = v.y;
            Bs[(kk + 2) * 128 + srow] = v.z;
            Bs[(kk + 3) * 128 + srow] = v.w;
        }
        __syncthreads();

        #pragma unroll 8
        for (int k = 0; k < 64; ++k) {
            const float4 a0 = *(const float4*)&As[k * 128 + ty * 8];
            const float4 a1 = *(const float4*)&As[k * 128 + ty * 8 + 4];
            const float4 bq0 = *(const float4*)&Bs[k * 128 + tx * 8];
            const float4 bq1 = *(const float4*)&Bs[k * 128 + tx * 8 + 4];
            float av[8] = {a0.x, a0.y, a0.z, a0.w, a1.x, a1.y, a1.z, a1.w};
            f2 bv[4];
            bv[0].x = bq0.x; bv[0].y = bq0.y;
            bv[1].x = bq0.z; bv[1].y = bq0.w;
            bv[2].x = bq1.x; bv[2].y = bq1.y;
            bv[3].x = bq1.z; bv[3].y = bq1.w;
            #pragma unroll
            for (int i = 0; i < 8; ++i) {
                f2 as; as.x = av[i]; as.y = av[i];
                #pragma unroll
                for (int jj = 0; jj < 4; ++jj) {
                    acc[i][jj] += as * bv[jj];   // v_pk_fma_f32
                }
            }
        }
    }

    float bias[8];
    #pragma unroll
    for (int jj = 0; jj < 8; ++jj)
        bias[jj] = bi[ncol + tx * 8 + jj] + bh[ncol + tx * 8 + jj];

    #pragma unroll
    for (int i = 0; i < 8; ++i) {
        int rr = r0 + ty * 8 + i;
        float* zp = Z + (size_t)rr * 1024 + dir * 512 + ncol + tx * 8;
        float4 o0, o1;
        o0.x = acc[i][0].x + bias[0]; o0.y = acc[i][0].y + bias[1];
        o0.z = acc[i][1].x + bias[2]; o0.w = acc[i][1].y + bias[3];
        o1.x = acc[i][2].x + bias[4]; o1.y = acc[i][2].y + bias[5];
        o1.z = acc[i][3].x + bias[6]; o1.w = acc[i][3].y + bias[7];
        *(float4*)zp       = o0;
        *(float4*)(zp + 4) = o1;
    }
}

// ---------------------------------------------------------------------------
// Kernel 2 (v5): LSTM recurrence, W arch-VGPR-resident.
// 128 blocks (batch x dir), 512 threads (8 waves).
// Octet o=q>>3 owns units uA=o, uB=o+64; lane r=q&7 owns k in [16r,16r+16).
// __launch_bounds__(512,1): VGPR budget 512 -> 128 w-floats live in ARCH
// VGPRs (r7's (512,2)=256-total budget pushed w into AGPRs: VGPR_Count=88,
// accvgpr_read per FMA operand ~tripled VALU issue).
// Unroll group 8: amortize the vmcnt(0)-before-barrier drain of Z prefetch
// loads and H store-acks over 8 steps.
// ---------------------------------------------------------------------------
#define UNR 8
__global__ __launch_bounds__(512, 1) void lstm_rec(
    const float* __restrict__ Z, const float* __restrict__ w_hh_f,
    const float* __restrict__ w_hh_r, float* __restrict__ H,
    float* __restrict__ ST, int base_f, int base_r, int L, int first)
{
    const int bid = blockIdx.x;
    const int b   = bid & 63;
    const int dir = bid >> 6;
    const int q   = threadIdx.x;
    const int r   = q & 7;    // k-slice lane
    const int o   = q >> 3;   // octet id = unit uA
    const int uA  = o;
    const int uB  = o + 64;

    const float* Whh = dir ? w_hh_r : w_hh_f;

    // register-resident weights: dot d=(u2*4+g), k in [16r,16r+16): 8 f2 each
    f2 w[8][8];
    #pragma unroll
    for (int u2 = 0; u2 < 2; ++u2) {
        const int u = u2 ? uB : uA;
        #pragma unroll
        for (int g = 0; g < 4; ++g) {
            const f2* src =
                (const f2*)(Whh + ((size_t)(g * 128 + u) * 128 + r * 16));
            #pragma unroll
            for (int i = 0; i < 8; ++i) w[u2 * 4 + g][i] = src[i];
        }
    }

    // h ping-pong: h[k] at chunk (k>>4)*20 + (k&15); chunk stride 20 floats
    __shared__ __align__(16) float sh_h[2][160];

    float* stp = ST + (size_t)(dir * 64 + b) * 256;
    if (q < 128)
        sh_h[0][(q >> 4) * 20 + (q & 15)] = first ? 0.0f : stp[q];
    float cA = first ? 0.0f : stp[128 + uA];
    float cB = first ? 0.0f : stp[128 + uB];

    // per-lane Z element: dot d=r -> u2=r>>2, g=r&3
    const float* Zbase = Z + (size_t)b * 1024 + dir * 512
                       + (r & 3) * 128 + o + ((r >> 2) << 6);
    float zcur[UNR], znxt[UNR];
    #pragma unroll
    for (int dt = 0; dt < UNR; ++dt) {
        const int s_loc = dir ? (L - 1 - dt) : dt;
        zcur[dt] = Zbase[(size_t)s_loc * 65536];
    }
    __syncthreads();

    float hAo[UNR], hBo[UNR];

    for (int t0 = 0; t0 < L; t0 += UNR) {
        const bool more = (t0 + UNR < L);
        if (more) {
            #pragma unroll
            for (int dt = 0; dt < UNR; ++dt) {
                const int tt = t0 + UNR + dt;
                const int s_loc = dir ? (L - 1 - tt) : tt;
                znxt[dt] = Zbase[(size_t)s_loc * 65536];
            }
        }

        #pragma unroll
        for (int dt = 0; dt < UNR; ++dt) {
            const int t = t0 + dt;
            // read this lane's 16-float h slice (4 conflict-free b128)
            const float4* hp = (const float4*)(&sh_h[t & 1][0] + r * 20);
            f2 hv[8];
            #pragma unroll
            for (int i = 0; i < 4; ++i) {
                float4 v = hp[i];
                hv[2 * i]     = *(const f2*)&v.x;
                hv[2 * i + 1] = *(const f2*)&v.z;
            }
            // 8 partial dots over 16 k, z injected in owning lane
            float zd[8];
            #pragma unroll
            for (int d = 0; d < 8; ++d) {
                f2 a = (f2)(0.0f);
                #pragma unroll
                for (int i = 0; i < 8; ++i)
                    a += w[d][i] * hv[i];        // v_pk_fma_f32
                float v = a.x + a.y;
                v += (d == r) ? zcur[dt] : 0.0f;
                zd[d] = v;
            }
            // 8-lane all-DPP butterfly: all lanes get all 8 full sums
            #pragma unroll
            for (int d = 0; d < 8; ++d) {
                float v = zd[d];
                v += quad_perm<QP_XOR1>(v);
                v += quad_perm<QP_XOR2>(v);
                v += quad_perm<QP_HMIRR>(v);
                zd[d] = v;
            }
            // gates (replicated across octet)
            float iA = sigm_f(zd[0]), fA = sigm_f(zd[1]);
            float gA = tanh_f(zd[2]), oA = sigm_f(zd[3]);
            cA = fA * cA + iA * gA;
            float hA = oA * tanh_f(cA);
            float iB = sigm_f(zd[4]), fB = sigm_f(zd[5]);
            float gB = tanh_f(zd[6]), oB = sigm_f(zd[7]);
            cB = fB * cB + iB * gB;
            float hB = oB * tanh_f(cB);
            hAo[dt] = hA; hBo[dt] = hB;

            float* hn = &sh_h[(t + 1) & 1][0];
            if (r == 0) hn[(uA >> 4) * 20 + (uA & 15)] = hA;
            if (r == 1) hn[(uB >> 4) * 20 + (uB & 15)] = hB;
            __syncthreads();
        }

        // buffered H stores (drain amortized over UNR steps)
        #pragma unroll
        for (int dt = 0; dt < UNR; ++dt) {
            const int t = t0 + dt;
            const int s_glob = dir ? (base_r + (L - 1 - t)) : (base_f + t);
            float* hg = H + ((size_t)s_glob * 64 + b) * 256 + dir * 128;
            if (r == 0) hg[uA] = hAo[dt];
            if (r == 1) hg[uB] = hBo[dt];
        }
        if (more) {
            #pragma unroll
            for (int dt = 0; dt < UNR; ++dt) zcur[dt] = znxt[dt];
        }
    }

    if (r == 0) { stp[uA] = hAo[UNR - 1]; stp[128 + uA] = cA; }
    if (r == 1) { stp[uB] = hBo[UNR - 1]; stp[128 + uB] = cB; }
}

// ---------------------------------------------------------------------------
// Kernel 3: emissions  F[r][t] = H[r] . w_out[t] + b_out[t]
// ---------------------------------------------------------------------------
__global__ __launch_bounds__(256) void emissions_k(
    const float* __restrict__ H, const float* __restrict__ w_out,
    const float* __restrict__ b_out, float* __restrict__ F)
{
    const int gid = blockIdx.x * 256 + threadIdx.x;
    const int r   = gid >> 2;
    const int tg  = gid & 3;
    const float4* h4 = (const float4*)(H + (size_t)r * 256);
    const float4* w4 = (const float4*)(w_out + (size_t)tg * 256);
    float a0 = 0.f, a1 = 0.f, a2 = 0.f, a3 = 0.f;
    #pragma unroll 8
    for (int k = 0; k < 64; ++k) {
        float4 h = h4[k], w = w4[k];
        a0 = fmaf(h.x, w.x, a0); a1 = fmaf(h.y, w.y, a1);
        a2 = fmaf(h.z, w.z, a2); a3 = fmaf(h.w, w.w, a3);
    }
    F[gid] = ((a0 + a1) + (a2 + a3)) + b_out[tg];
}

// ---------------------------------------------------------------------------
// Kernel 4: Viterbi. One block (1 wave) per batch.
// ---------------------------------------------------------------------------
__device__ __forceinline__ unsigned compose_map(unsigned a, unsigned b) {
    unsigned r = 0;
    #pragma unroll
    for (int jj = 0; jj < 4; ++jj) {
        unsigned bj = (b >> (jj * 8)) & 3u;
        unsigned aj = (a >> (bj * 8)) & 3u;
        r |= aj << (jj * 8);
    }
    return r;
}

__global__ __launch_bounds__(64) void viterbi_k(
    const float* __restrict__ F, const float* __restrict__ start_t,
    const float* __restrict__ end_t, const float* __restrict__ trans,
    int* __restrict__ out)
{
    const int b    = blockIdx.x;
    const int lane = threadIdx.x;
    __shared__ __align__(16) float sfeat[SLEN][NTAG];
    __shared__ unsigned sbp[SLEN];

    #pragma unroll
    for (int i = 0; i < 16; ++i) {
        int s = i * 64 + lane;
        ((float4*)sfeat)[s] = *(const float4*)(F + ((size_t)s * BATCH + b) * NTAG);
    }
    __syncthreads();

    const int cur = lane & 3;
    float tr0 = trans[0 * 4 + cur], tr1 = trans[1 * 4 + cur];
    float tr2 = trans[2 * 4 + cur], tr3 = trans[3 * 4 + cur];
    float sc = start_t[cur] + sfeat[0][cur];

    for (int s = 1; s < SLEN; ++s) {
        float ft = sfeat[s][cur];
        float s0 = __shfl(sc, 0), s1 = __shfl(sc, 1);
        float s2 = __shfl(sc, 2), s3 = __shfl(sc, 3);
        float c0 = s0 + tr0, c1 = s1 + tr1, c2 = s2 + tr2, c3 = s3 + tr3;
        float best = c0; int arg = 0;
        if (c1 > best) { best = c1; arg = 1; }
        if (c2 > best) { best = c2; arg = 2; }
        if (c3 > best) { best = c3; arg = 3; }
        sc = best + ft;
        unsigned bp = (unsigned)arg;
        unsigned b0 = __shfl(bp, 0), b1 = __shfl(bp, 1);
        unsigned b2 = __shfl(bp, 2), b3 = __shfl(bp, 3);
        if (lane == 0) sbp[s] = b0 | (b1 << 8) | (b2 << 16) | (b3 << 24);
    }
    sc += end_t[cur];
    float f0 = __shfl(sc, 0), f1 = __shfl(sc, 1);
    float f2v = __shfl(sc, 2), f3 = __shfl(sc, 3);
    int last = 0; float bb = f0;
    if (f1 > bb)  { bb = f1;  last = 1; }
    if (f2v > bb) { bb = f2v; last = 2; }
    if (f3 > bb)  { bb = f3;  last = 3; }
    __syncthreads();

    unsigned m[16];
    #pragma unroll
    for (int k = 0; k < 16; ++k) {
        int s = lane * 16 + k;
        m[k] = (s >= 1) ? sbp[s] : 0x03020100u;
    }
    unsigned G = m[15];
    #pragma unroll
    for (int k = 14; k >= 0; --k) G = compose_map(m[k], G);
    unsigned R = G;
    #pragma unroll
    for (int d = 1; d < 64; d <<= 1) {
        unsigned oo = __shfl_down(R, d);
        if (lane + d < 64) R = compose_map(R, oo);
    }
    unsigned P = __shfl_down(R, 1);
    if (lane == 63) P = 0x03020100u;

    int tcur = (int)((P >> (last * 8)) & 3u);
    int* ob = out + b * SLEN + lane * 16;
    ob[15] = tcur;
    #pragma unroll
    for (int k = 15; k >= 1; --k) {
        tcur = (int)((m[k] >> (tcur * 8)) & 3u);
        ob[k - 1] = tcur;
    }
}

// ---------------------------------------------------------------------------
extern "C" void kernel_launch(void* const* d_in, const int* in_sizes, int n_in,
                              void* d_out, int out_size, void* d_ws, size_t ws_size,
                              hipStream_t stream)
{
    const int*   sent    = (const int*)d_in[0];
    const float* embed   = (const float*)d_in[1];
    const float* w_ih_f  = (const float*)d_in[2];
    const float* w_hh_f  = (const float*)d_in[3];
    const float* b_ih_f  = (const float*)d_in[4];
    const float* b_hh_f  = (const float*)d_in[5];
    const float* w_ih_r  = (const float*)d_in[6];
    const float* w_hh_r  = (const float*)d_in[7];
    const float* b_ih_r  = (const float*)d_in[8];
    const float* b_hh_r  = (const float*)d_in[9];
    const float* w_out   = (const float*)d_in[10];
    const float* b_out   = (const float*)d_in[11];
    const float* start_t = (const float*)d_in[12];
    const float* end_t   = (const float*)d_in[13];
    const float* trans   = (const float*)d_in[14];
    int* out = (int*)d_out;

    const size_t H_FLOATS  = (size_t)SLEN * BATCH * 256;   // 16777216
    const size_t F_FLOATS  = (size_t)SLEN * BATCH * NTAG;  //   262144
    const size_t ST_FLOATS = (size_t)2 * BATCH * 256;      //    32768
    const size_t FIXED = H_FLOATS + F_FLOATS + ST_FLOATS;

    int L = SLEN;
    while (L > 32) {
        size_t need = ((size_t)L * BATCH * 1024 + FIXED) * sizeof(float);
        if (need <= ws_size) break;
        L >>= 1;
    }

    float* Z  = (float*)d_ws;
    float* H  = Z + (size_t)L * BATCH * 1024;
    float* F  = H + H_FLOATS;
    float* ST = F + F_FLOATS;

    const int nch = SLEN / L;
    for (int c = 0; c < nch; ++c) {
        const int base_f = c * L;
        const int base_r = SLEN - (c + 1) * L;
        gemm_zin<<<dim3(L / 2, 8), 256, 0, stream>>>(
            sent, embed, w_ih_f, w_ih_r, b_ih_f, b_hh_f, b_ih_r, b_hh_r,
            Z, base_f, base_r);
        lstm_rec<<<128, 512, 0, stream>>>(
            Z, w_hh_f, w_hh_r, H, ST, base_f, base_r, L, c == 0 ? 1 : 0);
    }
    emissions_k<<<1024, 256, 0, stream>>>(H, w_out, b_out, F);
    viterbi_k<<<64, 64, 0, stream>>>(F, start_t, end_t, trans, out);
}